// Round 3
// baseline (1796.611 us; speedup 1.0000x reference)
//
#include <hip/hip_runtime.h>

// ============================================================================
// Wired CfC (NCP) scan, B=256 x T=1024, 3 layers (hid 135/89/32) + final FC.
//
// Round 7: rounds 3-6 proved the kernel is L2-BW-bound on register-spill
// reloads: ~46 hot dwords/lane re-read per tick = 188 KB/CU/tick -> L2-bound
// tick = 1.40us (measured 1.63us). Three attribute levers (waves_per_eu,
// launch_bounds 2nd arg, LDS occupancy forcer) all failed to lift the
// 64-VGPR allocation. Per-lane weight demand is irreducibly 84 VGPRs at the
// 1024-thread workgroup max (4 lanes/unit), so REDUCE DEMAND instead:
//   - Wa+Wb (folded, f16) moves to LDS: waL[256][224] = 112 KB (shared by
//     the block, read 7 x ds_read_b128/lane/tick). Also forces 1 wg/CU.
//   - W1/W2 stay register-resident as 56 HAND-NAMED half2v variables
//     (macro-generated, no arrays -> no SROA/promotion failure possible).
//   - amdgpu_num_vgpr(96): direct budget request (harmless if ignored).
// Demand ~83 regs. Even at a hard 64 budget, spill traffic drops ~2.5x;
// at 96, zero spill. Expect WRITE_SIZE 70MB -> <20MB, dur 1670 -> 700-950us.
//
// Design: persistent-RNN, 256 blocks x 1024 threads (1 batch row per block),
// output unit = tid>>2, K-quarter = tid&3 (56 of KPAD=224 per lane).
// Per tick: 7 x { ds_read_b128 xcat (4-way broadcast) + ds_read_b128 Wa +
// 12 v_dot2_f32_f16 }, quad-combine via __shfl_xor(1)+__shfl_xor(2), fast
// tanh/sigmoid, blend. Layers pipelined across ticks -> ONE barrier/tick.
// ============================================================================

typedef _Float16 half2v __attribute__((ext_vector_type(2)));
typedef _Float16 half8v __attribute__((ext_vector_type(8)));

#define NBLK   256
#define NTHR   1024
#define TSTEPS 1024
#define KPAD   224
#define KQUAR  56
#define NKB    7       // KQUAR / 8 blocks per lane

struct Ptrs {
    const float* x;
    const unsigned int* msk[3];   // bool in reference -> int32 on device
    const float* W1[3];
    const float* W2[3];
    const float* Wa[3];
    const float* Wb[3];
    const float* b1[3];
    const float* b2[3];
    const float* ba[3];
    const float* bb[3];
    const float* fcW;
    const float* fcb;
};

__device__ __forceinline__ float fexp2(float x) {
#if __has_builtin(__builtin_amdgcn_exp2f)
    return __builtin_amdgcn_exp2f(x);
#else
    return exp2f(x);
#endif
}
__device__ __forceinline__ float frcp(float x) {
#if __has_builtin(__builtin_amdgcn_rcpf)
    return __builtin_amdgcn_rcpf(x);
#else
    return 1.0f / x;
#endif
}
// sigmoid(x) = 1/(1+2^(-x*log2e)); tanh(x) = 2/(1+2^(-2x*log2e)) - 1
__device__ __forceinline__ float fsig(float x) {
    return frcp(1.0f + fexp2(-1.442695041f * x));
}
__device__ __forceinline__ float ftanh(float x) {
    return 2.0f * frcp(1.0f + fexp2(-2.885390082f * x)) - 1.0f;
}

#if __has_builtin(__builtin_amdgcn_fdot2)
#define FD(a, b, c) __builtin_amdgcn_fdot2((a), (b), (c), false)
#else
__device__ __forceinline__ float fd_fallback(half2v a, half2v b, float c) {
    return c + (float)a[0] * (float)b[0] + (float)a[1] * (float)b[1];
}
#define FD(a, b, c) fd_fallback((a), (b), (c))
#endif

__device__ __forceinline__ half2v h2(_Float16 a, _Float16 b) { return half2v{a, b}; }

// Fold one (masked) weight pair to f16, zero beyond the real K.
__device__ __forceinline__ half2v fold2(const float* Wp, const unsigned int* mkp,
                                        int nK, int K, int k0) {
    float u0 = 0.f, u1 = 0.f;
    if (k0 < K) {
        const int i0 = nK + k0;
        u0 = Wp[i0] * ((mkp[i0] != 0u) ? 1.0f : 0.0f);
    }
    if (k0 + 1 < K) {
        const int i1 = nK + k0 + 1;
        u1 = Wp[i1] * ((mkp[i1] != 0u) ? 1.0f : 0.0f);
    }
    return h2((_Float16)u0, (_Float16)u1);
}

// 8 named half2 registers per K-block per matrix (no arrays -> no scratch).
#define DECL_KB(kb) \
    const half2v w1_##kb##_0 = fold2(W1p, mkp, nK, K, koff + kb * 8 + 0); \
    const half2v w1_##kb##_1 = fold2(W1p, mkp, nK, K, koff + kb * 8 + 2); \
    const half2v w1_##kb##_2 = fold2(W1p, mkp, nK, K, koff + kb * 8 + 4); \
    const half2v w1_##kb##_3 = fold2(W1p, mkp, nK, K, koff + kb * 8 + 6); \
    const half2v w2_##kb##_0 = fold2(W2p, mkp, nK, K, koff + kb * 8 + 0); \
    const half2v w2_##kb##_1 = fold2(W2p, mkp, nK, K, koff + kb * 8 + 2); \
    const half2v w2_##kb##_2 = fold2(W2p, mkp, nK, K, koff + kb * 8 + 4); \
    const half2v w2_##kb##_3 = fold2(W2p, mkp, nK, K, koff + kb * 8 + 6);

// One K-block: read x (broadcast) and Wa (distinct) from LDS, 12 dot2s.
#define DOT_KB(kb) { \
    const half8v xv = *(const half8v*)(srcp + kb * 8); \
    const half8v wv = *(const half8v*)(wap + kb * 8); \
    ac00 = FD(h2(xv[0], xv[1]), w1_##kb##_0, ac00); \
    ac10 = FD(h2(xv[0], xv[1]), w2_##kb##_0, ac10); \
    ac20 = FD(h2(xv[0], xv[1]), h2(wv[0], wv[1]), ac20); \
    ac01 = FD(h2(xv[2], xv[3]), w1_##kb##_1, ac01); \
    ac11 = FD(h2(xv[2], xv[3]), w2_##kb##_1, ac11); \
    ac21 = FD(h2(xv[2], xv[3]), h2(wv[2], wv[3]), ac21); \
    ac00 = FD(h2(xv[4], xv[5]), w1_##kb##_2, ac00); \
    ac10 = FD(h2(xv[4], xv[5]), w2_##kb##_2, ac10); \
    ac20 = FD(h2(xv[4], xv[5]), h2(wv[4], wv[5]), ac20); \
    ac01 = FD(h2(xv[6], xv[7]), w1_##kb##_3, ac01); \
    ac11 = FD(h2(xv[6], xv[7]), w2_##kb##_3, ac11); \
    ac21 = FD(h2(xv[6], xv[7]), h2(wv[6], wv[7]), ac21); \
}

__global__ __launch_bounds__(NTHR)
__attribute__((amdgpu_waves_per_eu(4, 4), amdgpu_num_vgpr(96)))
void cfc_kernel(Ptrs P, float* __restrict__ out) {
    // xc[parity][layer][k] : f16 concat inputs per layer, zero-padded to KPAD.
    __shared__ __align__(16) _Float16 xc[2][3][KPAD];   //   2688 B
    __shared__ __align__(16) _Float16 waL[256][KPAD];   // 114688 B (Wa+Wb folded)
    __shared__ __align__(16) float hn[256];             //   1024 B

    const int tid  = threadIdx.x;
    const int b    = blockIdx.x;
    const int unit = tid >> 2;   // output unit 0..255
    const int q    = tid & 3;    // which K-quarter this lane owns

    // ---- unit role: which layer / which row ----
    int L, n;
    if (unit < 135)      { L = 0; n = unit; }
    else if (unit < 224) { L = 1; n = unit - 135; }
    else                 { L = 2; n = unit - 224; }
    const int K    = (L == 0) ? 199 : ((L == 1) ? 224 : 121);
    const int HOFF = (L == 0) ? 0   : ((L == 1) ? 135 : 224);

    // ---- zero xc (padding regions must read as 0.0) ----
    {
        int* z = (int*)&xc[0][0][0];
        for (int i = tid; i < 2 * 3 * KPAD / 2; i += NTHR) z[i] = 0;
    }

    // ---- x staging: threads 960..1023 own one of the 64 input features ----
    const int xlane = tid - (NTHR - 64);
    float xpend = 0.0f;

    // ---- weight preload ----
    const float* W1p        = P.W1[L];
    const float* W2p        = P.W2[L];
    const float* Wap        = P.Wa[L];
    const float* Wbp        = P.Wb[L];
    const unsigned int* mkp = P.msk[L];
    const int nK   = n * K;
    const int koff = q * KQUAR;

    // W1/W2 (mask-folded) -> 56 named half2 registers
    DECL_KB(0) DECL_KB(1) DECL_KB(2) DECL_KB(3) DECL_KB(4) DECL_KB(5) DECL_KB(6)

    // Wa+Wb folded -> LDS (each lane writes its own 56-elem chunk)
#pragma unroll
    for (int i = 0; i < KQUAR / 2; ++i) {
        const int k0 = koff + 2 * i;
        float a0 = 0.f, a1 = 0.f;
        if (k0 < K)     a0 = Wap[nK + k0] + Wbp[nK + k0];
        if (k0 + 1 < K) a1 = Wap[nK + k0 + 1] + Wbp[nK + k0 + 1];
        *(half2v*)&waL[unit][k0] = h2((_Float16)a0, (_Float16)a1);
    }

    const float bv1 = P.b1[L][n];
    const float bv2 = P.b2[L][n];
    const float bva = P.ba[L][n] + P.bb[L][n];

    if (xlane >= 0) {
        xc[0][0][xlane] = (_Float16)P.x[((size_t)b * TSTEPS + 0) * 64 + xlane];
        xpend           = P.x[((size_t)b * TSTEPS + 1) * 64 + xlane];
    }
    __syncthreads();

    // loop-invariant LDS pointers
    const _Float16* wap = &waL[unit][koff];
    const _Float16* s0p = &xc[0][L][koff];
    const _Float16* s1p = &xc[1][L][koff];

    // ---- main scan: layer L computes timestep (tick - L); 1 barrier/tick ----
    for (int tick = 0; tick < TSTEPS + 2; ++tick) {
        // stage x(tick+1) (loaded 1 tick ago), prefetch x(tick+2)
        if (xlane >= 0) {
            if (tick + 1 < TSTEPS)
                xc[(tick + 1) & 1][0][xlane] = (_Float16)xpend;
            if (tick + 2 < TSTEPS)
                xpend = P.x[((size_t)b * TSTEPS + (tick + 2)) * 64 + xlane];
        }

        const int s = tick - L;
        if (s >= 0 && s < TSTEPS) {
            const _Float16* srcp = (s & 1) ? s1p : s0p;
            float ac00 = 0.f, ac01 = 0.f, ac10 = 0.f, ac11 = 0.f, ac20 = 0.f, ac21 = 0.f;
            DOT_KB(0) DOT_KB(1) DOT_KB(2) DOT_KB(3) DOT_KB(4) DOT_KB(5) DOT_KB(6)

            // combine the four K-quarters (quad = adjacent lanes in-wave)
            float s1 = ac00 + ac01;
            float s2 = ac10 + ac11;
            float sa = ac20 + ac21;
            s1 += __shfl_xor(s1, 1, 64);
            s2 += __shfl_xor(s2, 1, 64);
            sa += __shfl_xor(sa, 1, 64);
            s1 += __shfl_xor(s1, 2, 64);
            s2 += __shfl_xor(s2, 2, 64);
            sa += __shfl_xor(sa, 2, 64);
            // all four lanes now hold identical sums -> identical h
            const float f1 = ftanh(s1 + bv1);
            const float f2 = ftanh(s2 + bv2);
            const float tg = fsig(sa + bva);
            const float h  = f1 + tg * (f2 - f1);
            const _Float16 hv = (_Float16)h;

            const int pA = s & 1;        // consumer at timestep s (next layer)
            const int pB = (s + 1) & 1;  // consumer at timestep s+1 (own recurrence)
            // split the two stores across the quad
            if (q == 0) {
                if (L == 0)      xc[pA][1][n] = hv;        // -> layer1 input part
                else if (L == 1) xc[pA][2][n] = hv;        // -> layer2 input part
                if (s == TSTEPS - 1) hn[HOFF + n] = h;     // fp32 final state
            } else if (q == 1) {
                if (L == 0)      xc[pB][0][64 + n]  = hv;  // own recurrence
                else if (L == 1) xc[pB][1][135 + n] = hv;
                else             xc[pB][2][89 + n]  = hv;
            }
        }
        __syncthreads();
    }

    // ---- FC epilogue: out[b][o] = dot(hn, fcW[o,:]) + fcb[o], K-split quad ----
    {
        const int o = unit;
        const float4* wr = (const float4*)(P.fcW + (size_t)o * 256 + q * 64);
        const float4* hr = (const float4*)(hn + q * 64);
        float acc = (q == 0) ? P.fcb[o] : 0.0f;
#pragma unroll
        for (int d = 0; d < 16; ++d) {
            const float4 a = hr[d];
            const float4 w = wr[d];
            acc += a.x * w.x + a.y * w.y + a.z * w.z + a.w * w.w;
        }
        acc += __shfl_xor(acc, 1, 64);
        acc += __shfl_xor(acc, 2, 64);
        if (q == 0) out[(size_t)b * 256 + o] = acc;
    }
}

extern "C" void kernel_launch(void* const* d_in, const int* in_sizes, int n_in,
                              void* d_out, int out_size, void* d_ws, size_t ws_size,
                              hipStream_t stream) {
    (void)in_sizes; (void)n_in; (void)out_size; (void)d_ws; (void)ws_size;
    Ptrs P;
    P.x = (const float*)d_in[0];
    for (int l = 0; l < 3; ++l) {
        const int base = 1 + l * 9;
        P.msk[l] = (const unsigned int*)d_in[base + 0];
        P.W1[l]  = (const float*)d_in[base + 1];
        P.W2[l]  = (const float*)d_in[base + 2];
        P.Wa[l]  = (const float*)d_in[base + 3];
        P.Wb[l]  = (const float*)d_in[base + 4];
        P.b1[l]  = (const float*)d_in[base + 5];
        P.b2[l]  = (const float*)d_in[base + 6];
        P.ba[l]  = (const float*)d_in[base + 7];
        P.bb[l]  = (const float*)d_in[base + 8];
    }
    P.fcW = (const float*)d_in[28];
    P.fcb = (const float*)d_in[29];

    hipLaunchKernelGGL(cfc_kernel, dim3(NBLK), dim3(NTHR), 0, stream,
                       P, (float*)d_out);
}

// Round 4
// 1648.830 us; speedup vs baseline: 1.0896x; 1.0896x over previous
//
#include <hip/hip_runtime.h>

// ============================================================================
// Wired CfC (NCP) scan, B=256 x T=1024, 3 layers (hid 135/89/32) + final FC.
//
// Round 8: empirical law from rounds 3-7: the backend ALWAYS budgets VGPRs
// for 2 workgroups/CU (512thr -> 128 VGPRs, 1024thr -> 64) and no attribute
// moves it. Round 7 (named vars, zero arrays) proved it's budget, not
// SROA/promotion. So design to the grant:
//   - 512 threads/block -> 128-VGPR grant (empirical).
//   - K-half split (pair = unit, half = K-half of 112): W1+W2 register-
//     resident = 112 half2 regs; Wa+Wb folded -> LDS (f16).
//   - Demand ~130-140 vs 128 -> spill ~5-12 dwords (was 53); per-tick L2
//     reload 188KB/CU -> <25KB/CU. New cost: 14 ds_read_b128 of Wa per
//     lane per tick (112KB/CU/tick of LDS traffic, ~0.4us/tick, overlaps
//     the 672-cyc VALU dot floor).
//   - Wa rows padded to 232 f16 (464B): lane (2u+h) b128 start bank =
//     (116u+56h+4kb)%32 -> 8 distinct mod-4 start banks, all 32 banks
//     covered evenly -> conflict-free 8-clk reads (stride 224 would pile
//     16 lanes on a bank quartet).
// Predict: WRITE_SIZE 55.7MB -> <15MB, dur 1847 -> 500-800us.
//
// Design: persistent-RNN, 256 blocks x 512 threads (1 batch row per block),
// unit = tid>>1, K-half = tid&1. Per tick: 14 x { broadcast ds_read_b128
// xcat + distinct ds_read_b128 Wa + 12 v_dot2_f32_f16 }, pair-combine via
// __shfl_xor(1), fast tanh/sigmoid, blend. Layers pipelined across ticks
// -> ONE barrier/tick. Ping-pong f16 xcat in LDS; x prefetched 2 ahead.
// ============================================================================

typedef _Float16 half2v __attribute__((ext_vector_type(2)));
typedef _Float16 half8v __attribute__((ext_vector_type(8)));

#define NBLK   256
#define NTHR   512
#define TSTEPS 1024
#define KPAD   224
#define WSTRIDE 232    // Wa LDS row stride in f16 (16B-aligned, bank-spread)
#define KHALF  112
#define NKB    14      // KHALF / 8 blocks per lane

struct Ptrs {
    const float* x;
    const unsigned int* msk[3];   // bool in reference -> int32 on device
    const float* W1[3];
    const float* W2[3];
    const float* Wa[3];
    const float* Wb[3];
    const float* b1[3];
    const float* b2[3];
    const float* ba[3];
    const float* bb[3];
    const float* fcW;
    const float* fcb;
};

__device__ __forceinline__ float fexp2(float x) {
#if __has_builtin(__builtin_amdgcn_exp2f)
    return __builtin_amdgcn_exp2f(x);
#else
    return exp2f(x);
#endif
}
__device__ __forceinline__ float frcp(float x) {
#if __has_builtin(__builtin_amdgcn_rcpf)
    return __builtin_amdgcn_rcpf(x);
#else
    return 1.0f / x;
#endif
}
// sigmoid(x) = 1/(1+2^(-x*log2e)); tanh(x) = 2/(1+2^(-2x*log2e)) - 1
__device__ __forceinline__ float fsig(float x) {
    return frcp(1.0f + fexp2(-1.442695041f * x));
}
__device__ __forceinline__ float ftanh(float x) {
    return 2.0f * frcp(1.0f + fexp2(-2.885390082f * x)) - 1.0f;
}

#if __has_builtin(__builtin_amdgcn_fdot2)
#define FD(a, b, c) __builtin_amdgcn_fdot2((a), (b), (c), false)
#else
__device__ __forceinline__ float fd_fallback(half2v a, half2v b, float c) {
    return c + (float)a[0] * (float)b[0] + (float)a[1] * (float)b[1];
}
#define FD(a, b, c) fd_fallback((a), (b), (c))
#endif

__device__ __forceinline__ half2v h2(_Float16 a, _Float16 b) { return half2v{a, b}; }

// Fold one (masked) weight pair to f16, zero beyond the real K.
__device__ __forceinline__ half2v fold2(const float* Wp, const unsigned int* mkp,
                                        int nK, int K, int k0) {
    float u0 = 0.f, u1 = 0.f;
    if (k0 < K) {
        const int i0 = nK + k0;
        u0 = Wp[i0] * ((mkp[i0] != 0u) ? 1.0f : 0.0f);
    }
    if (k0 + 1 < K) {
        const int i1 = nK + k0 + 1;
        u1 = Wp[i1] * ((mkp[i1] != 0u) ? 1.0f : 0.0f);
    }
    return h2((_Float16)u0, (_Float16)u1);
}

// 8 named half2 registers per K-block (W1 + W2); Wa comes from LDS.
#define DECL_KB(kb) \
    const half2v w1_##kb##_0 = fold2(W1p, mkp, nK, K, koff + kb * 8 + 0); \
    const half2v w1_##kb##_1 = fold2(W1p, mkp, nK, K, koff + kb * 8 + 2); \
    const half2v w1_##kb##_2 = fold2(W1p, mkp, nK, K, koff + kb * 8 + 4); \
    const half2v w1_##kb##_3 = fold2(W1p, mkp, nK, K, koff + kb * 8 + 6); \
    const half2v w2_##kb##_0 = fold2(W2p, mkp, nK, K, koff + kb * 8 + 0); \
    const half2v w2_##kb##_1 = fold2(W2p, mkp, nK, K, koff + kb * 8 + 2); \
    const half2v w2_##kb##_2 = fold2(W2p, mkp, nK, K, koff + kb * 8 + 4); \
    const half2v w2_##kb##_3 = fold2(W2p, mkp, nK, K, koff + kb * 8 + 6);

// One K-block: x broadcast + Wa distinct from LDS, 12 dot2s.
#define DOT_KB(kb) { \
    const half8v xv = *(const half8v*)(srcp + kb * 8); \
    const half8v wv = *(const half8v*)(wap + kb * 8); \
    ac00 = FD(h2(xv[0], xv[1]), w1_##kb##_0, ac00); \
    ac10 = FD(h2(xv[0], xv[1]), w2_##kb##_0, ac10); \
    ac20 = FD(h2(xv[0], xv[1]), h2(wv[0], wv[1]), ac20); \
    ac01 = FD(h2(xv[2], xv[3]), w1_##kb##_1, ac01); \
    ac11 = FD(h2(xv[2], xv[3]), w2_##kb##_1, ac11); \
    ac21 = FD(h2(xv[2], xv[3]), h2(wv[2], wv[3]), ac21); \
    ac00 = FD(h2(xv[4], xv[5]), w1_##kb##_2, ac00); \
    ac10 = FD(h2(xv[4], xv[5]), w2_##kb##_2, ac10); \
    ac20 = FD(h2(xv[4], xv[5]), h2(wv[4], wv[5]), ac20); \
    ac01 = FD(h2(xv[6], xv[7]), w1_##kb##_3, ac01); \
    ac11 = FD(h2(xv[6], xv[7]), w2_##kb##_3, ac11); \
    ac21 = FD(h2(xv[6], xv[7]), h2(wv[6], wv[7]), ac21); \
}

__global__ __launch_bounds__(NTHR, 2)
void cfc_kernel(Ptrs P, float* __restrict__ out) {
    // xc[parity][layer][k] : f16 concat inputs per layer, zero-padded to KPAD.
    __shared__ __align__(16) _Float16 xc[2][3][KPAD];      //   2688 B
    __shared__ __align__(16) _Float16 waL[256][WSTRIDE];   // 118784 B (Wa+Wb)
    __shared__ __align__(16) float hn[256];                //   1024 B

    const int tid  = threadIdx.x;
    const int b    = blockIdx.x;
    const int unit = tid >> 1;   // output unit 0..255
    const int half = tid & 1;    // which K-half this lane owns

    // ---- unit role: which layer / which row ----
    int L, n;
    if (unit < 135)      { L = 0; n = unit; }
    else if (unit < 224) { L = 1; n = unit - 135; }
    else                 { L = 2; n = unit - 224; }
    const int K    = (L == 0) ? 199 : ((L == 1) ? 224 : 121);
    const int HOFF = (L == 0) ? 0   : ((L == 1) ? 135 : 224);

    // ---- zero xc (padding regions must read as 0.0) ----
    {
        int* z = (int*)&xc[0][0][0];
        for (int i = tid; i < 2 * 3 * KPAD / 2; i += NTHR) z[i] = 0;
    }

    // ---- weight preload ----
    const float* W1p        = P.W1[L];
    const float* W2p        = P.W2[L];
    const float* Wap        = P.Wa[L];
    const float* Wbp        = P.Wb[L];
    const unsigned int* mkp = P.msk[L];
    const int nK   = n * K;
    const int koff = half * KHALF;

    // W1/W2 (mask-folded) -> 112 named half2 registers
    DECL_KB(0)  DECL_KB(1)  DECL_KB(2)  DECL_KB(3)  DECL_KB(4)
    DECL_KB(5)  DECL_KB(6)  DECL_KB(7)  DECL_KB(8)  DECL_KB(9)
    DECL_KB(10) DECL_KB(11) DECL_KB(12) DECL_KB(13)

    // Wa+Wb folded -> LDS (each lane writes its own K-half chunk)
#pragma unroll
    for (int i = 0; i < KHALF / 2; ++i) {
        const int k0 = koff + 2 * i;
        float a0 = 0.f, a1 = 0.f;
        if (k0 < K)     a0 = Wap[nK + k0] + Wbp[nK + k0];
        if (k0 + 1 < K) a1 = Wap[nK + k0 + 1] + Wbp[nK + k0 + 1];
        *(half2v*)&waL[unit][k0] = h2((_Float16)a0, (_Float16)a1);
    }

    const float bv1 = P.b1[L][n];
    const float bv2 = P.b2[L][n];
    const float bva = P.ba[L][n] + P.bb[L][n];

    // ---- x staging: threads 448..511 own one of the 64 input features ----
    const int xlane = tid - (NTHR - 64);
    float xpend = 0.0f;
    if (xlane >= 0) {
        xc[0][0][xlane] = (_Float16)P.x[((size_t)b * TSTEPS + 0) * 64 + xlane];
        xpend           = P.x[((size_t)b * TSTEPS + 1) * 64 + xlane];
    }
    __syncthreads();

    // loop-invariant LDS pointers
    const _Float16* wap = &waL[unit][koff];
    const _Float16* s0p = &xc[0][L][koff];
    const _Float16* s1p = &xc[1][L][koff];

    // ---- main scan: layer L computes timestep (tick - L); 1 barrier/tick ----
    for (int tick = 0; tick < TSTEPS + 2; ++tick) {
        // stage x(tick+1) (loaded 1 tick ago), prefetch x(tick+2)
        if (xlane >= 0) {
            if (tick + 1 < TSTEPS)
                xc[(tick + 1) & 1][0][xlane] = (_Float16)xpend;
            if (tick + 2 < TSTEPS)
                xpend = P.x[((size_t)b * TSTEPS + (tick + 2)) * 64 + xlane];
        }

        const int s = tick - L;
        if (s >= 0 && s < TSTEPS) {
            const _Float16* srcp = (s & 1) ? s1p : s0p;
            float ac00 = 0.f, ac01 = 0.f, ac10 = 0.f, ac11 = 0.f, ac20 = 0.f, ac21 = 0.f;
            DOT_KB(0)  DOT_KB(1)  DOT_KB(2)  DOT_KB(3)  DOT_KB(4)
            DOT_KB(5)  DOT_KB(6)  DOT_KB(7)  DOT_KB(8)  DOT_KB(9)
            DOT_KB(10) DOT_KB(11) DOT_KB(12) DOT_KB(13)

            // combine the two K-halves (pairs are adjacent lanes in-wave)
            float s1 = ac00 + ac01;
            float s2 = ac10 + ac11;
            float sa = ac20 + ac21;
            s1 += __shfl_xor(s1, 1, 64);
            s2 += __shfl_xor(s2, 1, 64);
            sa += __shfl_xor(sa, 1, 64);
            // both lanes now hold identical sums -> identical h
            const float f1 = ftanh(s1 + bv1);
            const float f2 = ftanh(s2 + bv2);
            const float tg = fsig(sa + bva);
            const float h  = f1 + tg * (f2 - f1);
            const _Float16 hv = (_Float16)h;

            const int pA = s & 1;        // consumer at timestep s (next layer)
            const int pB = (s + 1) & 1;  // consumer at timestep s+1 (own recurrence)
            // split the two stores across the lane pair
            if (half == 0) {
                if (L == 0)      xc[pA][1][n] = hv;        // -> layer1 input part
                else if (L == 1) xc[pA][2][n] = hv;        // -> layer2 input part
                if (s == TSTEPS - 1) hn[HOFF + n] = h;     // fp32 final state
            } else {
                if (L == 0)      xc[pB][0][64 + n]  = hv;  // own recurrence
                else if (L == 1) xc[pB][1][135 + n] = hv;
                else             xc[pB][2][89 + n]  = hv;
            }
        }
        __syncthreads();
    }

    // ---- FC epilogue: out[b][o] = dot(hn, fcW[o,:]) + fcb[o], K-split pair ----
    {
        const int o = unit;
        const float4* wr = (const float4*)(P.fcW + (size_t)o * 256 + half * 128);
        const float4* hr = (const float4*)(hn + half * 128);
        float acc = half ? 0.0f : P.fcb[o];
#pragma unroll 8
        for (int d = 0; d < 32; ++d) {
            const float4 a = hr[d];
            const float4 w = wr[d];
            acc += a.x * w.x + a.y * w.y + a.z * w.z + a.w * w.w;
        }
        acc += __shfl_xor(acc, 1, 64);
        if (half == 0) out[(size_t)b * 256 + o] = acc;
    }
}

extern "C" void kernel_launch(void* const* d_in, const int* in_sizes, int n_in,
                              void* d_out, int out_size, void* d_ws, size_t ws_size,
                              hipStream_t stream) {
    (void)in_sizes; (void)n_in; (void)out_size; (void)d_ws; (void)ws_size;
    Ptrs P;
    P.x = (const float*)d_in[0];
    for (int l = 0; l < 3; ++l) {
        const int base = 1 + l * 9;
        P.msk[l] = (const unsigned int*)d_in[base + 0];
        P.W1[l]  = (const float*)d_in[base + 1];
        P.W2[l]  = (const float*)d_in[base + 2];
        P.Wa[l]  = (const float*)d_in[base + 3];
        P.Wb[l]  = (const float*)d_in[base + 4];
        P.b1[l]  = (const float*)d_in[base + 5];
        P.b2[l]  = (const float*)d_in[base + 6];
        P.ba[l]  = (const float*)d_in[base + 7];
        P.bb[l]  = (const float*)d_in[base + 8];
    }
    P.fcW = (const float*)d_in[28];
    P.fcb = (const float*)d_in[29];

    hipLaunchKernelGGL(cfc_kernel, dim3(NBLK), dim3(NTHR), 0, stream,
                       P, (float*)d_out);
}

// Round 5
// 1563.793 us; speedup vs baseline: 1.1489x; 1.0544x over previous
//
#include <hip/hip_runtime.h>

// ============================================================================
// Wired CfC (NCP) scan, B=256 x T=1024, 3 layers (hid 135/89/32) + final FC.
//
// Round 9: revert to the verified round-0 structure (512thr, ALL 3 weight
// matrices register-resident, ~53 dword spill tolerated -> reloads ride the
// VMEM/L2 pipe which OVERLAPS LDS+VALU; measured 1463-1472us). Round 8
// proved the Wa->LDS offload serializes onto the single 100B/cyc LDS pipe
// (229KB/CU/tick = 2290+ cyc) and is a net loss (1694us, 122M conflicts).
//
// New this round: halve the LDS xcat traffic via DPP sharing.
//   - Units 2j/2j+1 with the same K-half need IDENTICAL x blocks; they sit
//     in one quad (lane = 2*unit+half). Each lane reads 7 of 14 b128 blocks
//     (alternating by unit parity) and gets the other 7 from lane^2 via
//     v_mov_dpp quad_perm(2,3,0,1) - VALU pipe, not LDS.
//   - Weights preloaded in own/other block order -> no selects.
//   - The single layer-straddling quad (units 134/135) sits in wave 4:
//     ALL of wave 4 takes a direct 14-read path (wave-uniform branch).
//   - Pair-combine __shfl_xor (ds_swizzle, LDS) -> quad_perm(1,0,3,2) DPP.
// LDS/CU/tick: 1344 -> ~700 cyc; VALU +~60 cyc/wave. Predict 1200-1380us.
// ============================================================================

typedef _Float16 half2v __attribute__((ext_vector_type(2)));
typedef _Float16 half8v __attribute__((ext_vector_type(8)));
typedef int      int4v  __attribute__((ext_vector_type(4)));

#define NBLK   256
#define NTHR   512
#define TSTEPS 1024
#define KPAD   224
#define KHALF  112

struct Ptrs {
    const float* x;
    const unsigned int* msk[3];   // bool in reference -> int32 on device
    const float* W1[3];
    const float* W2[3];
    const float* Wa[3];
    const float* Wb[3];
    const float* b1[3];
    const float* b2[3];
    const float* ba[3];
    const float* bb[3];
    const float* fcW;
    const float* fcb;
};

__device__ __forceinline__ float fexp2(float x) {
#if __has_builtin(__builtin_amdgcn_exp2f)
    return __builtin_amdgcn_exp2f(x);
#else
    return exp2f(x);
#endif
}
__device__ __forceinline__ float frcp(float x) {
#if __has_builtin(__builtin_amdgcn_rcpf)
    return __builtin_amdgcn_rcpf(x);
#else
    return 1.0f / x;
#endif
}
// sigmoid(x) = 1/(1+2^(-x*log2e)); tanh(x) = 2/(1+2^(-2x*log2e)) - 1
__device__ __forceinline__ float fsig(float x) {
    return frcp(1.0f + fexp2(-1.442695041f * x));
}
__device__ __forceinline__ float ftanh(float x) {
    return 2.0f * frcp(1.0f + fexp2(-2.885390082f * x)) - 1.0f;
}

#if __has_builtin(__builtin_amdgcn_fdot2)
#define FD(a, b, c) __builtin_amdgcn_fdot2((a), (b), (c), false)
#else
__device__ __forceinline__ float fd_fallback(half2v a, half2v b, float c) {
    return c + (float)a[0] * (float)b[0] + (float)a[1] * (float)b[1];
}
#define FD(a, b, c) fd_fallback((a), (b), (c))
#endif

__device__ __forceinline__ half2v h2(_Float16 a, _Float16 b) { return half2v{a, b}; }

// quad_perm(2,3,0,1): fetch lane^2's value (unit-partner within quad). VALU.
__device__ __forceinline__ half8v dpp_xor2(half8v v) {
    int4v a = __builtin_bit_cast(int4v, v);
    int4v r;
    r[0] = __builtin_amdgcn_update_dpp(0, a[0], 0x4E, 0xF, 0xF, true);
    r[1] = __builtin_amdgcn_update_dpp(0, a[1], 0x4E, 0xF, 0xF, true);
    r[2] = __builtin_amdgcn_update_dpp(0, a[2], 0x4E, 0xF, 0xF, true);
    r[3] = __builtin_amdgcn_update_dpp(0, a[3], 0x4E, 0xF, 0xF, true);
    return __builtin_bit_cast(half8v, r);
}
// quad_perm(1,0,3,2): x + lane^1's x (K-half pair combine). VALU.
__device__ __forceinline__ float pair_sum(float x) {
    const int v = __builtin_amdgcn_update_dpp(
        0, __builtin_bit_cast(int, x), 0xB1, 0xF, 0xF, true);
    return x + __builtin_bit_cast(float, v);
}

// Fold one (masked) weight pair to f16, zero beyond the real K.
__device__ __forceinline__ half2v fold2(const float* Wp, const unsigned int* mkp,
                                        int nK, int K, int k0) {
    float u0 = 0.f, u1 = 0.f;
    if (k0 < K) {
        const int i0 = nK + k0;
        u0 = Wp[i0] * ((mkp[i0] != 0u) ? 1.0f : 0.0f);
    }
    if (k0 + 1 < K) {
        const int i1 = nK + k0 + 1;
        u1 = Wp[i1] * ((mkp[i1] != 0u) ? 1.0f : 0.0f);
    }
    return h2((_Float16)u0, (_Float16)u1);
}

// 24 dot2s for block-pair m: own blocks with xo_, partner blocks with xt_.
#define DOTS(m, xo_, xt_) { \
    const half2v o0 = h2(xo_[0], xo_[1]), o1 = h2(xo_[2], xo_[3]); \
    const half2v o2 = h2(xo_[4], xo_[5]), o3 = h2(xo_[6], xo_[7]); \
    const half2v t0 = h2(xt_[0], xt_[1]), t1 = h2(xt_[2], xt_[3]); \
    const half2v t2 = h2(xt_[4], xt_[5]), t3 = h2(xt_[6], xt_[7]); \
    ac00 = FD(o0, w1o[4*(m)+0], ac00);  ac01 = FD(t0, w1t[4*(m)+0], ac01); \
    ac10 = FD(o0, w2o[4*(m)+0], ac10);  ac11 = FD(t0, w2t[4*(m)+0], ac11); \
    ac20 = FD(o0, wao[4*(m)+0], ac20);  ac21 = FD(t0, wat[4*(m)+0], ac21); \
    ac00 = FD(o1, w1o[4*(m)+1], ac00);  ac01 = FD(t1, w1t[4*(m)+1], ac01); \
    ac10 = FD(o1, w2o[4*(m)+1], ac10);  ac11 = FD(t1, w2t[4*(m)+1], ac11); \
    ac20 = FD(o1, wao[4*(m)+1], ac20);  ac21 = FD(t1, wat[4*(m)+1], ac21); \
    ac00 = FD(o2, w1o[4*(m)+2], ac00);  ac01 = FD(t2, w1t[4*(m)+2], ac01); \
    ac10 = FD(o2, w2o[4*(m)+2], ac10);  ac11 = FD(t2, w2t[4*(m)+2], ac11); \
    ac20 = FD(o2, wao[4*(m)+2], ac20);  ac21 = FD(t2, wat[4*(m)+2], ac21); \
    ac00 = FD(o3, w1o[4*(m)+3], ac00);  ac01 = FD(t3, w1t[4*(m)+3], ac01); \
    ac10 = FD(o3, w2o[4*(m)+3], ac10);  ac11 = FD(t3, w2t[4*(m)+3], ac11); \
    ac20 = FD(o3, wao[4*(m)+3], ac20);  ac21 = FD(t3, wat[4*(m)+3], ac21); \
}

__global__ __launch_bounds__(NTHR)
__attribute__((amdgpu_waves_per_eu(2, 2)))
void cfc_kernel(Ptrs P, float* __restrict__ out) {
    // xc[parity][layer][k] : f16 concat inputs per layer, zero-padded to KPAD.
    __shared__ __align__(16) _Float16 xc[2][3][KPAD];
    __shared__ __align__(16) float hn[256];

    const int tid  = threadIdx.x;
    const int b    = blockIdx.x;
    const int unit = tid >> 1;   // output unit 0..255
    const int half = tid & 1;    // which K-half this lane owns
    const int up   = unit & 1;   // block-parity this lane reads itself

    // wave 4 (tid 256..319) contains the layer-straddling quad (units 134/135)
    // -> whole wave takes the direct path (wave-uniform, no divergence).
    const bool direct = ((tid >> 6) == 4);

    // ---- pair role: one output unit ----
    int L, n;
    if (unit < 135)      { L = 0; n = unit; }
    else if (unit < 224) { L = 1; n = unit - 135; }
    else                 { L = 2; n = unit - 224; }
    const int K    = (L == 0) ? 199 : ((L == 1) ? 224 : 121);
    const int HOFF = (L == 0) ? 0   : ((L == 1) ? 135 : 224);

    // ---- zero LDS (padding regions must read as 0.0) ----
    {
        int* z = (int*)&xc[0][0][0];
        for (int i = tid; i < 2 * 3 * KPAD / 2; i += NTHR) z[i] = 0;
    }
    __syncthreads();

    // ---- x staging: threads 448..511 own one of the 64 input features ----
    const int xlane = tid - 448;
    float xpend = 0.0f;
    if (xlane >= 0) {
        xc[0][0][xlane] = (_Float16)P.x[((size_t)b * TSTEPS + 0) * 64 + xlane];
        xpend           = P.x[((size_t)b * TSTEPS + 1) * 64 + xlane];
    }

    // ---- weight preload: own/other block order; fold mask, fold Wa+Wb ----
    const float* W1p        = P.W1[L];
    const float* W2p        = P.W2[L];
    const float* Wap        = P.Wa[L];
    const float* Wbp        = P.Wb[L];
    const unsigned int* mkp = P.msk[L];
    const int nK   = n * K;
    const int koff = half * KHALF;

    half2v w1o[28], w1t[28], w2o[28], w2t[28], wao[28], wat[28];
#pragma unroll
    for (int m = 0; m < 7; ++m) {
#pragma unroll
        for (int j = 0; j < 4; ++j) {
            const int ko = koff + (2 * m + up) * 8 + 2 * j;      // own block
            const int kt = koff + (2 * m + 1 - up) * 8 + 2 * j;  // partner block
            w1o[m * 4 + j] = fold2(W1p, mkp, nK, K, ko);
            w1t[m * 4 + j] = fold2(W1p, mkp, nK, K, kt);
            w2o[m * 4 + j] = fold2(W2p, mkp, nK, K, ko);
            w2t[m * 4 + j] = fold2(W2p, mkp, nK, K, kt);
            {
                float a0 = 0.f, a1 = 0.f;
                if (ko < K)     a0 = Wap[nK + ko] + Wbp[nK + ko];
                if (ko + 1 < K) a1 = Wap[nK + ko + 1] + Wbp[nK + ko + 1];
                wao[m * 4 + j] = h2((_Float16)a0, (_Float16)a1);
            }
            {
                float a0 = 0.f, a1 = 0.f;
                if (kt < K)     a0 = Wap[nK + kt] + Wbp[nK + kt];
                if (kt + 1 < K) a1 = Wap[nK + kt + 1] + Wbp[nK + kt + 1];
                wat[m * 4 + j] = h2((_Float16)a0, (_Float16)a1);
            }
        }
    }
    const float bv1 = P.b1[L][n];
    const float bv2 = P.b2[L][n];
    const float bva = P.ba[L][n] + P.bb[L][n];
    __syncthreads();

    // ---- main scan: layer L computes timestep (tick - L); 1 barrier/tick ----
    for (int tick = 0; tick < TSTEPS + 2; ++tick) {
        // stage x(tick+1) (loaded 1 tick ago), prefetch x(tick+2)
        if (xlane >= 0) {
            if (tick + 1 < TSTEPS)
                xc[(tick + 1) & 1][0][xlane] = (_Float16)xpend;
            if (tick + 2 < TSTEPS)
                xpend = P.x[((size_t)b * TSTEPS + (tick + 2)) * 64 + xlane];
        }

        const int s = tick - L;
        if (s >= 0 && s < TSTEPS) {
            const _Float16* srcp = &xc[s & 1][L][koff];
            const _Float16* po   = srcp + up * 8;        // own-parity blocks
            const _Float16* pt   = srcp + (1 - up) * 8;  // partner-parity blocks
            float ac00 = 0.f, ac01 = 0.f, ac10 = 0.f, ac11 = 0.f, ac20 = 0.f, ac21 = 0.f;
            if (!direct) {
                // read 7 blocks, get the other 7 from lane^2 via DPP (VALU)
#pragma unroll
                for (int m = 0; m < 7; ++m) {
                    const half8v xown = *(const half8v*)(po + m * 16);
                    const half8v xoth = dpp_xor2(xown);
                    DOTS(m, xown, xoth);
                }
            } else {
                // wave 4: direct 14-block read (contains mixed-layer quad)
#pragma unroll
                for (int m = 0; m < 7; ++m) {
                    const half8v xown = *(const half8v*)(po + m * 16);
                    const half8v xoth = *(const half8v*)(pt + m * 16);
                    DOTS(m, xown, xoth);
                }
            }

            // combine the two K-halves (pairs are adjacent lanes) via DPP
            const float s1 = pair_sum(ac00 + ac01);
            const float s2 = pair_sum(ac10 + ac11);
            const float sa = pair_sum(ac20 + ac21);
            // both lanes now hold identical sums -> identical h
            const float f1 = ftanh(s1 + bv1);
            const float f2 = ftanh(s2 + bv2);
            const float tg = fsig(sa + bva);
            const float h  = f1 + tg * (f2 - f1);
            const _Float16 hv = (_Float16)h;

            const int pA = s & 1;        // consumer at timestep s (next layer)
            const int pB = (s + 1) & 1;  // consumer at timestep s+1 (own recurrence)
            // split the two stores across the lane pair
            if (half == 0) {
                if (L == 0)      xc[pA][1][n] = hv;        // -> layer1 input part
                else if (L == 1) xc[pA][2][n] = hv;        // -> layer2 input part
                if (s == TSTEPS - 1) hn[HOFF + n] = h;     // fp32 final state
            } else {
                if (L == 0)      xc[pB][0][64 + n]  = hv;  // own recurrence
                else if (L == 1) xc[pB][1][135 + n] = hv;
                else             xc[pB][2][89 + n]  = hv;
            }
        }
        __syncthreads();
    }

    // ---- FC epilogue: out[b][o] = dot(hn, fcW[o,:]) + fcb[o], K-split pair ----
    {
        const int o = unit;
        const float4* wr = (const float4*)(P.fcW + (size_t)o * 256 + half * 128);
        const float4* hr = (const float4*)(hn + half * 128);
        float acc = half ? 0.0f : P.fcb[o];
#pragma unroll 8
        for (int d = 0; d < 32; ++d) {
            const float4 a = hr[d];
            const float4 w = wr[d];
            acc += a.x * w.x + a.y * w.y + a.z * w.z + a.w * w.w;
        }
        acc = pair_sum(acc);
        if (half == 0) out[(size_t)b * 256 + o] = acc;
    }
}

extern "C" void kernel_launch(void* const* d_in, const int* in_sizes, int n_in,
                              void* d_out, int out_size, void* d_ws, size_t ws_size,
                              hipStream_t stream) {
    (void)in_sizes; (void)n_in; (void)out_size; (void)d_ws; (void)ws_size;
    Ptrs P;
    P.x = (const float*)d_in[0];
    for (int l = 0; l < 3; ++l) {
        const int base = 1 + l * 9;
        P.msk[l] = (const unsigned int*)d_in[base + 0];
        P.W1[l]  = (const float*)d_in[base + 1];
        P.W2[l]  = (const float*)d_in[base + 2];
        P.Wa[l]  = (const float*)d_in[base + 3];
        P.Wb[l]  = (const float*)d_in[base + 4];
        P.b1[l]  = (const float*)d_in[base + 5];
        P.b2[l]  = (const float*)d_in[base + 6];
        P.ba[l]  = (const float*)d_in[base + 7];
        P.bb[l]  = (const float*)d_in[base + 8];
    }
    P.fcW = (const float*)d_in[28];
    P.fcb = (const float*)d_in[29];

    hipLaunchKernelGGL(cfc_kernel, dim3(NBLK), dim3(NTHR), 0, stream,
                       P, (float*)d_out);
}